// Round 14
// baseline (152.371 us; speedup 1.0000x reference)
//
#include <hip/hip_runtime.h>

typedef unsigned short u16;
typedef unsigned int u32;
typedef short bf16x8 __attribute__((ext_vector_type(8)));
typedef float f32x4 __attribute__((ext_vector_type(4)));

#define CIN 256
#define COUT 256

__device__ __forceinline__ u16 f2b(float f) {   // f32 -> bf16 RNE
  u32 u = __float_as_uint(f);
  u += 0x7fffu + ((u >> 16) & 1u);
  return (u16)(u >> 16);
}
__device__ __forceinline__ u32 packbf(float lo, float hi) {
  return (u32)f2b(lo) | ((u32)f2b(hi) << 16);
}
__device__ __forceinline__ u32 bil2(u32 u00, u32 u01, u32 u10, u32 u11, float4 wt) {
  float s0 = __uint_as_float(u00 << 16) * wt.x;
  s0 = fmaf(__uint_as_float(u01 << 16), wt.y, s0);
  s0 = fmaf(__uint_as_float(u10 << 16), wt.z, s0);
  s0 = fmaf(__uint_as_float(u11 << 16), wt.w, s0);
  float s1 = __uint_as_float(u00 & 0xffff0000u) * wt.x;
  s1 = fmaf(__uint_as_float(u01 & 0xffff0000u), wt.y, s1);
  s1 = fmaf(__uint_as_float(u10 & 0xffff0000u), wt.z, s1);
  s1 = fmaf(__uint_as_float(u11 & 0xffff0000u), wt.w, s1);
  return packbf(s0, s1);
}
// barrier that does NOT drain vmcnt: LDS-visibility only.
__device__ __forceinline__ void bar() {
  asm volatile("s_waitcnt lgkmcnt(0)\n\ts_barrier" ::: "memory");
}

// -------- K0 (fused prep): g<1024: xT transpose tile; else weight permute ----
__global__ __launch_bounds__(256) void k_prep(
    const float* __restrict__ x, const float* __restrict__ w_mod,
    const float* __restrict__ w_def,
    u16* __restrict__ xT, u16* __restrict__ Wm2, u16* __restrict__ W2) {
  __shared__ __align__(16) char SB[9216];
  int t = threadIdx.x, g = blockIdx.x;
  if (g < 1024) {            // x NCHW f32 -> xT[b][pos][c] bf16
    u16 (*T)[72] = (u16(*)[72])SB;
    int b = g >> 8, ct = (g >> 6) & 3, pt = g & 63;
    int c0 = ct << 6, pos0 = pt << 6;
    {
      int cl = t >> 2, pb = (t & 3) << 4;
      const float* p = x + (((b << 8) + c0 + cl) << 12) + pos0 + pb;
#pragma unroll
      for (int i = 0; i < 4; ++i) {
        float4 v = *(const float4*)(p + i * 4);
        int pp = pb + i * 4;
        T[pp][cl] = f2b(v.x); T[pp + 1][cl] = f2b(v.y);
        T[pp + 2][cl] = f2b(v.z); T[pp + 3][cl] = f2b(v.w);
      }
    }
    __syncthreads();
    {
      int pl = t >> 2, q = t & 3;
      u16* dst = xT + (((b << 12) + pos0 + pl) << 8) + c0 + (q << 4);
      *(uint4*)dst = *(const uint4*)&T[pl][q << 4];
      *(uint4*)(dst + 8) = *(const uint4*)&T[pl][(q << 4) + 8];
    }
  } else {                   // weight permute + f32->bf16
    float* L = (float*)SB;
    int gg = g - 1024;
    if (gg < 256) {
      const float* src = w_def + gg * 2304;
      for (int j = t; j < 2304; j += 256) L[j] = src[j];
      __syncthreads();
      u16* dst = W2 + gg * 2304;
      for (int j = t; j < 2304; j += 256) {
        int kk = j >> 8, c = j & 255;
        dst[j] = f2b(L[c * 9 + kk]);
      }
    } else {
      int cm = gg - 256;
      if (cm < 27) {
        const float* src = w_mod + cm * 2304;
        for (int j = t; j < 2304; j += 256) L[j] = src[j];
      }
      __syncthreads();
      u16* dst = Wm2 + cm * 2304;
      for (int j = t; j < 2304; j += 256) {
        int kk = j >> 8, c = j & 255;
        dst[j] = (cm < 27) ? f2b(L[c * 9 + kk]) : (u16)0;
      }
    }
  }
}

// -------- K1+K2 FUSED, 1024 threads (16 waves = 4/SIMD) ---------------------
// Phase 1 NEW: 4-way split-K — ALL 16 waves active. Group h = t>>8 (0..3)
// owns chunks [9h, 9h+9): 4 pair-iterations + 1 tail chunk (hazards
// separated by one barrier; barrier count uniform across all waves).
// Per-group geometry byte-identical to the verified 2-group code.
// mods reduction sums 4 partials (f32 regroup only, ~1e-6 perturbation).
// Phase 2: VERBATIM round-12 (16 waves, dual-half staging, 4-buf single-bar,
// deep A-prefetch). LDS: As1 4x18432=73728 | mods2 4x8448=33792 -> LB 107520;
// As2 (36864) reuses As1 region; Ci/Cw outside. Total 118.5 KB (<160 KB).
__global__ __launch_bounds__(1024) void k_fused(
    const u16* __restrict__ xT, const u16* __restrict__ Wm2,
    const u16* __restrict__ W2, const float* __restrict__ b_def,
    float* __restrict__ out) {
  __shared__ __align__(16) char LB[107520];
  __shared__ __align__(16) int2 Ci[576];
  __shared__ __align__(16) float4 Cw[576];
  u16 (*As1)[2][64][72] = (u16 (*)[2][64][72])LB;           // phase 1: 4 grps
  float (*mods2)[32][66] = (float (*)[32][66])(LB + 73728); // phase 1 partials
  u16 (*As2)[64][72] = (u16 (*)[64][72])LB;                 // phase 2: 4 bufs

  int t = threadIdx.x;
  int l = t & 63;
  int w = t >> 6;          // 0..15
  int g = blockIdx.x;
  int b = (g & 7) >> 1, y = ((g >> 3) << 1) + (g & 1);
  const u16* xTb = xT + (b << 20);
  int ml = l & 15, kq = l >> 4;

  // ============ phase 1: mod conv, 4-way split-K (all 16 waves) ============
  {
    int h = t >> 8;          // K-group 0..3, chunks [9h, 9h+9)
    int wl = (t >> 6) & 3;
    int tg = t & 255;
    int px = tg >> 2, q = tg & 3;
    f32x4 zero = {0.f, 0.f, 0.f, 0.f};
    f32x4 acc0 = zero, acc1 = zero;
    uint4 VA0, VA1, VB0, VB1;
    uint4 S0, S1, S2, S3, T0, T1, T2, T3;

#define MC_ISSUE_A(i, V0, V1)                                                \
  { int ch_ = h * 9 + (i); int kk_ = ch_ >> 2, c0_ = (ch_ & 3) << 6;         \
    int ky_ = kk_ / 3, kx_ = kk_ - 3 * ky_;                                  \
    int ys_ = y + ky_ - 1, xs_ = px + kx_ - 1;                               \
    V0 = make_uint4(0, 0, 0, 0); V1 = V0;                                    \
    if (ys_ >= 0 && ys_ < 64 && xs_ >= 0 && xs_ < 64) {                      \
      const u16* p_ = xTb + (((ys_ << 6) + xs_) << 8) + c0_ + (q << 4);      \
      V0 = *(const uint4*)p_; V1 = *(const uint4*)(p_ + 8);                  \
    } }

#define MC_ISSUE_B(i, R0, R1, R2, R3)                                        \
  { int ch_ = h * 9 + (i); int kk_ = ch_ >> 2, c0_ = (ch_ & 3) << 6;         \
    const u16* pw_ = Wm2 + (kk_ << 8) + c0_ + (kq << 3);                     \
    R0 = *(const uint4*)(pw_ + ml * 2304);                                   \
    R1 = *(const uint4*)(pw_ + (16 + ml) * 2304);                            \
    R2 = *(const uint4*)(pw_ + ml * 2304 + 32);                              \
    R3 = *(const uint4*)(pw_ + (16 + ml) * 2304 + 32); }

#define MC_WRITE(buf, V0, V1)                                                \
  { *(uint4*)&As1[h][buf][px][q << 4] = V0;                                  \
    *(uint4*)&As1[h][buf][px][(q << 4) + 8] = V1; }

#define MC_MFMA(buf, R0, R1, R2, R3)                                         \
  { bf16x8 a0_ = *(const bf16x8*)&As1[h][buf][wl * 16 + ml][kq << 3];        \
    acc0 = __builtin_amdgcn_mfma_f32_16x16x32_bf16(a0_, *(const bf16x8*)&R0, acc0, 0,0,0); \
    acc1 = __builtin_amdgcn_mfma_f32_16x16x32_bf16(a0_, *(const bf16x8*)&R1, acc1, 0,0,0); \
    bf16x8 a1_ = *(const bf16x8*)&As1[h][buf][wl * 16 + ml][32 + (kq << 3)]; \
    acc0 = __builtin_amdgcn_mfma_f32_16x16x32_bf16(a1_, *(const bf16x8*)&R2, acc0, 0,0,0); \
    acc1 = __builtin_amdgcn_mfma_f32_16x16x32_bf16(a1_, *(const bf16x8*)&R3, acc1, 0,0,0); }

    MC_ISSUE_A(0, VA0, VA1)
    MC_ISSUE_A(1, VB0, VB1)
    MC_ISSUE_B(0, S0, S1, S2, S3)
#pragma unroll 1
    for (int i2 = 0; i2 < 8; i2 += 2) {
      MC_WRITE(0, VA0, VA1)
      bar();
      MC_ISSUE_A(i2 + 2, VA0, VA1)          // i2+2 in {2,4,6,8}, always < 9
      MC_ISSUE_B(i2 + 1, T0, T1, T2, T3)
      MC_MFMA(0, S0, S1, S2, S3)
      MC_WRITE(1, VB0, VB1)
      bar();
      if (i2 + 3 < 9) MC_ISSUE_A(i2 + 3, VB0, VB1)
      MC_ISSUE_B(i2 + 2, S0, S1, S2, S3)    // i2+2 < 9 always
      MC_MFMA(1, T0, T1, T2, T3)
    }
    // tail: chunk 9h+8 (VA holds A(8), S holds B(8)); WRITE(0) is one
    // barrier after buffer-0's last read (MFMA(0) at i2=6, before that bar).
    MC_WRITE(0, VA0, VA1)
    bar();
    MC_MFMA(0, S0, S1, S2, S3)
#pragma unroll
    for (int r = 0; r < 4; ++r) {
      mods2[h][ml][wl * 16 + kq * 4 + r]      = acc0[r];
      mods2[h][16 + ml][wl * 16 + kq * 4 + r] = acc1[r];
    }
#undef MC_ISSUE_A
#undef MC_ISSUE_B
#undef MC_WRITE
#undef MC_MFMA
  }
  __syncthreads();
  if (t < 576) {
    int kk = t >> 6, pxx_i = t & 63;
    float dy = mods2[0][2 * kk][pxx_i] + mods2[1][2 * kk][pxx_i]
             + mods2[2][2 * kk][pxx_i] + mods2[3][2 * kk][pxx_i];
    float dx = mods2[0][2 * kk + 1][pxx_i] + mods2[1][2 * kk + 1][pxx_i]
             + mods2[2][2 * kk + 1][pxx_i] + mods2[3][2 * kk + 1][pxx_i];
    float mv = mods2[0][18 + kk][pxx_i] + mods2[1][18 + kk][pxx_i]
             + mods2[2][18 + kk][pxx_i] + mods2[3][18 + kk][pxx_i];
    float msk = 1.f / (1.f + __expf(-mv));
    int ky = kk / 3, kx = kk - 3 * ky;
    float py  = dy + (float)(y + ky - 1);
    float pxx = dx + (float)(pxx_i + kx - 1);
    float y0f = floorf(py), x0f = floorf(pxx);
    float fy = py - y0f, fx = pxx - x0f;
    int y0 = (int)y0f, x0 = (int)x0f;
    float vy0 = (y0 >= 0 && y0 < 64) ? msk : 0.f;
    float vy1 = (y0 + 1 >= 0 && y0 + 1 < 64) ? msk : 0.f;
    float w00 = (1.f - fy) * (1.f - fx) * vy0;
    float w01 = (1.f - fy) * fx * vy0;
    float w10 = fy * (1.f - fx) * vy1;
    float w11 = fy * fx * vy1;
    int xb2 = min(max(x0, 0), 62);
    float wA0 = (xb2 == x0) ? w00 : ((xb2 == x0 + 1) ? w01 : 0.f);
    float wB0 = (xb2 + 1 == x0) ? w00 : ((xb2 + 1 == x0 + 1) ? w01 : 0.f);
    float wA1 = (xb2 == x0) ? w10 : ((xb2 == x0 + 1) ? w11 : 0.f);
    float wB1 = (xb2 + 1 == x0) ? w10 : ((xb2 + 1 == x0 + 1) ? w11 : 0.f);
    int ib0 = min(max(y0, 0), 63) * 64 + xb2;
    int ib1 = min(max(y0 + 1, 0), 63) * 64 + xb2;
    Ci[t] = make_int2(ib0, ib1);
    Cw[t] = make_float4(wA0, wB0, wA1, wB1);
  }
  __syncthreads();   // Ci/Cw visible; As1/mods2 dead -> As2 may reuse region

  // ===== phase 2: 16 waves, dual-half staging, 4-buf 1-bar, deep prefetch ==
  // VERBATIM round-12 (passed at 151.5 us).
  {
    int cp = t >> 9;                       // staging half: chunk parity
    int gm = (t >> 3) & 63, go = t & 7;    // round-9 mapping within each half
    int nrow0 = (w << 4) + ml;             // wave w: n in [w*16, w*16+16)

    f32x4 zero = {0.f, 0.f, 0.f, 0.f};
    f32x4 acc[4];
#pragma unroll
    for (int i = 0; i < 4; ++i) acc[i] = zero;

    uint4 A00, A01, A02, A03; float4 wt0;   // A set 0 (this half's even chunk)
    uint4 A10, A11, A12, A13; float4 wt1;   // A set 1 (this half's odd chunk)
    uint4 SA0, SA2;                         // B set S (chunk c4)
    uint4 SB0, SB2;                         // B set S' (chunk c4+1)
    uint4 TA0, TA2;                         // B set T (chunk c4+2)
    uint4 TB0, TB2;                         // B set T' (chunk c4+3)

#define ISSUE_A(chunk, a0, a1, a2, a3, wt)                                   \
  { int kk_ = (chunk) >> 2, c0_ = ((chunk) & 3) << 6;                        \
    int cI_ = (kk_ << 6) + gm;                                               \
    int2 ib_ = Ci[cI_];                                                      \
    wt = Cw[cI_];                                                            \
    const u16* p0_ = xTb + (ib_.x << 8) + c0_ + (go << 3);                   \
    const u16* p1_ = xTb + (ib_.y << 8) + c0_ + (go << 3);                   \
    a0 = *(const uint4*)p0_;  a1 = *(const uint4*)(p0_ + 256);               \
    a2 = *(const uint4*)p1_;  a3 = *(const uint4*)(p1_ + 256); }

#define ISSUE_B(chunk, R0, R2)                                               \
  { int kk_ = (chunk) >> 2, c0_ = ((chunk) & 3) << 6;                        \
    const u16* pw_ = W2 + (kk_ << 8) + c0_ + (kq << 3);                      \
    R0 = *(const uint4*)(pw_ + nrow0 * 2304);                                \
    R2 = *(const uint4*)(pw_ + nrow0 * 2304 + 32); }

#define UNPACK(CUR, a0, a1, a2, a3, wt)                                      \
  { u32 q0_ = bil2(a0.x, a1.x, a2.x, a3.x, wt);                              \
    u32 q1_ = bil2(a0.y, a1.y, a2.y, a3.y, wt);                              \
    u32 q2_ = bil2(a0.z, a1.z, a2.z, a3.z, wt);                              \
    u32 q3_ = bil2(a0.w, a1.w, a2.w, a3.w, wt);                              \
    *(uint4*)&As2[CUR][gm][go << 3] = make_uint4(q0_, q1_, q2_, q3_); }

#define DOMFMA(CUR, R0, R2)                                                  \
  { bf16x8 a0_ = *(const bf16x8*)&As2[CUR][ml][kq << 3];                     \
    bf16x8 a1_ = *(const bf16x8*)&As2[CUR][16 + ml][kq << 3];                \
    bf16x8 a2_ = *(const bf16x8*)&As2[CUR][32 + ml][kq << 3];                \
    bf16x8 a3_ = *(const bf16x8*)&As2[CUR][48 + ml][kq << 3];                \
    bf16x8 b0_ = *(const bf16x8*)&R0;                                        \
    acc[0] = __builtin_amdgcn_mfma_f32_16x16x32_bf16(a0_, b0_, acc[0], 0,0,0); \
    acc[1] = __builtin_amdgcn_mfma_f32_16x16x32_bf16(a1_, b0_, acc[1], 0,0,0); \
    acc[2] = __builtin_amdgcn_mfma_f32_16x16x32_bf16(a2_, b0_, acc[2], 0,0,0); \
    acc[3] = __builtin_amdgcn_mfma_f32_16x16x32_bf16(a3_, b0_, acc[3], 0,0,0); \
    a0_ = *(const bf16x8*)&As2[CUR][ml][32 + (kq << 3)];                     \
    a1_ = *(const bf16x8*)&As2[CUR][16 + ml][32 + (kq << 3)];                \
    a2_ = *(const bf16x8*)&As2[CUR][32 + ml][32 + (kq << 3)];                \
    a3_ = *(const bf16x8*)&As2[CUR][48 + ml][32 + (kq << 3)];                \
    b0_ = *(const bf16x8*)&R2;                                               \
    acc[0] = __builtin_amdgcn_mfma_f32_16x16x32_bf16(a0_, b0_, acc[0], 0,0,0); \
    acc[1] = __builtin_amdgcn_mfma_f32_16x16x32_bf16(a1_, b0_, acc[1], 0,0,0); \
    acc[2] = __builtin_amdgcn_mfma_f32_16x16x32_bf16(a2_, b0_, acc[2], 0,0,0); \
    acc[3] = __builtin_amdgcn_mfma_f32_16x16x32_bf16(a3_, b0_, acc[3], 0,0,0); }

    ISSUE_A(0 + cp, A00, A01, A02, A03, wt0)   // half cp stages chunk 0+cp
    ISSUE_A(2 + cp, A10, A11, A12, A13, wt1)   // and chunk 2+cp
    ISSUE_B(0, SA0, SA2)
    ISSUE_B(1, SB0, SB2)
#pragma unroll 1
    for (int p2 = 0; p2 < 9; ++p2) {
      int c4 = p2 << 2;
      // ---- even sub-iter: bufs 0,1 <- chunks c4, c4+1 (one per half) -----
      UNPACK(0 + cp, A00, A01, A02, A03, wt0)
      bar();
      if (p2 < 8) ISSUE_A(c4 + 4 + cp, A00, A01, A02, A03, wt0)
      ISSUE_B(c4 + 2, TA0, TA2)
      ISSUE_B(c4 + 3, TB0, TB2)
      DOMFMA(0, SA0, SA2)
      DOMFMA(1, SB0, SB2)
      // ---- odd sub-iter: bufs 2,3 <- chunks c4+2, c4+3 -------------------
      UNPACK(2 + cp, A10, A11, A12, A13, wt1)
      bar();
      if (p2 < 8) {
        ISSUE_A(c4 + 6 + cp, A10, A11, A12, A13, wt1)
        ISSUE_B(c4 + 4, SA0, SA2)
        ISSUE_B(c4 + 5, SB0, SB2)
      }
      DOMFMA(2, TA0, TA2)
      DOMFMA(3, TB0, TB2)
    }

    // epilogue (round-3 proven form): bias + f32 stores
    {
      int n = nrow0;
      float bias = b_def[n];
      float* op = out + (((b << 8) + n) << 12) + (y << 6);
#pragma unroll
      for (int mt = 0; mt < 4; ++mt) {
        float4 v;
        v.x = acc[mt][0] + bias;
        v.y = acc[mt][1] + bias;
        v.z = acc[mt][2] + bias;
        v.w = acc[mt][3] + bias;
        *(float4*)(op + mt * 16 + kq * 4) = v;
      }
    }
#undef ISSUE_A
#undef ISSUE_B
#undef UNPACK
#undef DOMFMA
  }
}

// -------------------- launcher --------------------
extern "C" void kernel_launch(void* const* d_in, const int* in_sizes, int n_in,
                              void* d_out, int out_size, void* d_ws, size_t ws_size,
                              hipStream_t stream) {
  const float* x     = (const float*)d_in[0];
  const float* w_mod = (const float*)d_in[1];
  const float* w_def = (const float*)d_in[2];
  const float* b_def = (const float*)d_in[3];
  float* out = (float*)d_out;
  char* ws = (char*)d_ws;
  // ws: xT 8,388,608 | W2 1,179,648 | Wm2 147,456
  u16* xT  = (u16*)(ws);
  u16* W2  = (u16*)(ws + 8388608);
  u16* Wm2 = (u16*)(ws + 8388608 + 1179648);

  hipLaunchKernelGGL(k_prep, dim3(1312), dim3(256), 0, stream, x, w_mod, w_def, xT, Wm2, W2);
  hipLaunchKernelGGL(k_fused, dim3(256), dim3(1024), 0, stream, xT, Wm2, W2, b_def, out);
}

// Round 16
// 137.425 us; speedup vs baseline: 1.1088x; 1.1088x over previous
//
#include <hip/hip_runtime.h>

typedef unsigned short u16;
typedef unsigned int u32;
typedef short bf16x8 __attribute__((ext_vector_type(8)));
typedef float f32x4 __attribute__((ext_vector_type(4)));

#define CIN 256
#define COUT 256

__device__ __forceinline__ u16 f2b(float f) {   // f32 -> bf16 RNE
  u32 u = __float_as_uint(f);
  u += 0x7fffu + ((u >> 16) & 1u);
  return (u16)(u >> 16);
}
__device__ __forceinline__ u32 packbf(float lo, float hi) {
  return (u32)f2b(lo) | ((u32)f2b(hi) << 16);
}
__device__ __forceinline__ u32 bil2(u32 u00, u32 u01, u32 u10, u32 u11, float4 wt) {
  float s0 = __uint_as_float(u00 << 16) * wt.x;
  s0 = fmaf(__uint_as_float(u01 << 16), wt.y, s0);
  s0 = fmaf(__uint_as_float(u10 << 16), wt.z, s0);
  s0 = fmaf(__uint_as_float(u11 << 16), wt.w, s0);
  float s1 = __uint_as_float(u00 & 0xffff0000u) * wt.x;
  s1 = fmaf(__uint_as_float(u01 & 0xffff0000u), wt.y, s1);
  s1 = fmaf(__uint_as_float(u10 & 0xffff0000u), wt.z, s1);
  s1 = fmaf(__uint_as_float(u11 & 0xffff0000u), wt.w, s1);
  return packbf(s0, s1);
}
// barrier that does NOT drain vmcnt: LDS-visibility only.
__device__ __forceinline__ void bar() {
  asm volatile("s_waitcnt lgkmcnt(0)\n\ts_barrier" ::: "memory");
}

// -------- K0 (fused prep): g<1024: xT transpose tile; else weight permute ----
// w_def now stored CHUNK-MAJOR: W4[ch][n][cl], ch=kk*4+(c>>6), cl=c&63
// (forward-only relocation of the same f2b value; bijective: 36x256x64 slots).
__global__ __launch_bounds__(256) void k_prep(
    const float* __restrict__ x, const float* __restrict__ w_mod,
    const float* __restrict__ w_def,
    u16* __restrict__ xT, u16* __restrict__ Wm2, u16* __restrict__ W2) {
  __shared__ __align__(16) char SB[9216];
  int t = threadIdx.x, g = blockIdx.x;
  if (g < 1024) {            // x NCHW f32 -> xT[b][pos][c] bf16
    u16 (*T)[72] = (u16(*)[72])SB;
    int b = g >> 8, ct = (g >> 6) & 3, pt = g & 63;
    int c0 = ct << 6, pos0 = pt << 6;
    {
      int cl = t >> 2, pb = (t & 3) << 4;
      const float* p = x + (((b << 8) + c0 + cl) << 12) + pos0 + pb;
#pragma unroll
      for (int i = 0; i < 4; ++i) {
        float4 v = *(const float4*)(p + i * 4);
        int pp = pb + i * 4;
        T[pp][cl] = f2b(v.x); T[pp + 1][cl] = f2b(v.y);
        T[pp + 2][cl] = f2b(v.z); T[pp + 3][cl] = f2b(v.w);
      }
    }
    __syncthreads();
    {
      int pl = t >> 2, q = t & 3;
      u16* dst = xT + (((b << 12) + pos0 + pl) << 8) + c0 + (q << 4);
      *(uint4*)dst = *(const uint4*)&T[pl][q << 4];
      *(uint4*)(dst + 8) = *(const uint4*)&T[pl][(q << 4) + 8];
    }
  } else {                   // weight permute + f32->bf16
    float* L = (float*)SB;
    int gg = g - 1024;
    if (gg < 256) {
      const float* src = w_def + gg * 2304;
      for (int j = t; j < 2304; j += 256) L[j] = src[j];
      __syncthreads();
      for (int j = t; j < 2304; j += 256) {
        int kk = j >> 8, c = j & 255;
        int ch = (kk << 2) + (c >> 6), cl = c & 63;
        W2[ch * 16384 + gg * 64 + cl] = f2b(L[c * 9 + kk]);
      }
    } else {
      int cm = gg - 256;
      if (cm < 27) {
        const float* src = w_mod + cm * 2304;
        for (int j = t; j < 2304; j += 256) L[j] = src[j];
      }
      __syncthreads();
      u16* dst = Wm2 + cm * 2304;
      for (int j = t; j < 2304; j += 256) {
        int kk = j >> 8, c = j & 255;
        dst[j] = (cm < 27) ? f2b(L[c * 9 + kk]) : (u16)0;
      }
    }
  }
}

// -------- K1+K2 FUSED, 1024 threads (16 waves = 4/SIMD) ---------------------
// Phase 1: round-14 4-way split-K (verbatim, old Wm2 layout). Phase 2:
// round-14 structure; B-path NEW: wave-contiguous 2KB loads from W4
// (2 instrs x 8x128B segments vs 32x64B scattered) + wave-private LDS slab
// redistribute inside DOMFMA (write [l>>3][(l&7)*8] pieces, read the
// verified [ml][kq*8] fragments; 72-u16 padded rows, <=2-way conflicts;
// no barrier interaction). A-path / schedule / accumulation order unchanged.
__global__ __launch_bounds__(1024) void k_fused(
    const u16* __restrict__ xT, const u16* __restrict__ Wm2,
    const u16* __restrict__ W2, const float* __restrict__ b_def,
    float* __restrict__ out) {
  __shared__ __align__(16) char LB[107520];
  __shared__ __align__(16) int2 Ci[576];
  __shared__ __align__(16) float4 Cw[576];
  u16 (*As1)[2][64][72] = (u16 (*)[2][64][72])LB;           // phase 1: 4 grps
  float (*mods2)[32][66] = (float (*)[32][66])(LB + 73728); // phase 1 partials
  u16 (*As2)[64][72] = (u16 (*)[64][72])LB;                 // phase 2: 4 bufs
  u16 (*Bsl)[16][72] = (u16 (*)[16][72])(LB + 36864);       // phase 2: B slabs

  int t = threadIdx.x;
  int l = t & 63;
  int w = t >> 6;          // 0..15
  int g = blockIdx.x;
  int b = (g & 7) >> 1, y = ((g >> 3) << 1) + (g & 1);
  const u16* xTb = xT + (b << 20);
  int ml = l & 15, kq = l >> 4;

  // ============ phase 1: mod conv, 4-way split-K (all 16 waves) ============
  {
    int h = t >> 8;          // K-group 0..3, chunks [9h, 9h+9)
    int wl = (t >> 6) & 3;
    int tg = t & 255;
    int px = tg >> 2, q = tg & 3;
    f32x4 zero = {0.f, 0.f, 0.f, 0.f};
    f32x4 acc0 = zero, acc1 = zero;
    uint4 VA0, VA1, VB0, VB1;
    uint4 S0, S1, S2, S3, T0, T1, T2, T3;

#define MC_ISSUE_A(i, V0, V1)                                                \
  { int ch_ = h * 9 + (i); int kk_ = ch_ >> 2, c0_ = (ch_ & 3) << 6;         \
    int ky_ = kk_ / 3, kx_ = kk_ - 3 * ky_;                                  \
    int ys_ = y + ky_ - 1, xs_ = px + kx_ - 1;                               \
    V0 = make_uint4(0, 0, 0, 0); V1 = V0;                                    \
    if (ys_ >= 0 && ys_ < 64 && xs_ >= 0 && xs_ < 64) {                      \
      const u16* p_ = xTb + (((ys_ << 6) + xs_) << 8) + c0_ + (q << 4);      \
      V0 = *(const uint4*)p_; V1 = *(const uint4*)(p_ + 8);                  \
    } }

#define MC_ISSUE_B(i, R0, R1, R2, R3)                                        \
  { int ch_ = h * 9 + (i); int kk_ = ch_ >> 2, c0_ = (ch_ & 3) << 6;         \
    const u16* pw_ = Wm2 + (kk_ << 8) + c0_ + (kq << 3);                     \
    R0 = *(const uint4*)(pw_ + ml * 2304);                                   \
    R1 = *(const uint4*)(pw_ + (16 + ml) * 2304);                            \
    R2 = *(const uint4*)(pw_ + ml * 2304 + 32);                              \
    R3 = *(const uint4*)(pw_ + (16 + ml) * 2304 + 32); }

#define MC_WRITE(buf, V0, V1)                                                \
  { *(uint4*)&As1[h][buf][px][q << 4] = V0;                                  \
    *(uint4*)&As1[h][buf][px][(q << 4) + 8] = V1; }

#define MC_MFMA(buf, R0, R1, R2, R3)                                         \
  { bf16x8 a0_ = *(const bf16x8*)&As1[h][buf][wl * 16 + ml][kq << 3];        \
    acc0 = __builtin_amdgcn_mfma_f32_16x16x32_bf16(a0_, *(const bf16x8*)&R0, acc0, 0,0,0); \
    acc1 = __builtin_amdgcn_mfma_f32_16x16x32_bf16(a0_, *(const bf16x8*)&R1, acc1, 0,0,0); \
    bf16x8 a1_ = *(const bf16x8*)&As1[h][buf][wl * 16 + ml][32 + (kq << 3)]; \
    acc0 = __builtin_amdgcn_mfma_f32_16x16x32_bf16(a1_, *(const bf16x8*)&R2, acc0, 0,0,0); \
    acc1 = __builtin_amdgcn_mfma_f32_16x16x32_bf16(a1_, *(const bf16x8*)&R3, acc1, 0,0,0); }

    MC_ISSUE_A(0, VA0, VA1)
    MC_ISSUE_A(1, VB0, VB1)
    MC_ISSUE_B(0, S0, S1, S2, S3)
#pragma unroll 1
    for (int i2 = 0; i2 < 8; i2 += 2) {
      MC_WRITE(0, VA0, VA1)
      bar();
      MC_ISSUE_A(i2 + 2, VA0, VA1)          // i2+2 in {2,4,6,8}, always < 9
      MC_ISSUE_B(i2 + 1, T0, T1, T2, T3)
      MC_MFMA(0, S0, S1, S2, S3)
      MC_WRITE(1, VB0, VB1)
      bar();
      if (i2 + 3 < 9) MC_ISSUE_A(i2 + 3, VB0, VB1)
      MC_ISSUE_B(i2 + 2, S0, S1, S2, S3)    // i2+2 < 9 always
      MC_MFMA(1, T0, T1, T2, T3)
    }
    // tail: chunk 9h+8 (VA holds A(8), S holds B(8)); WRITE(0) is one
    // barrier after buffer-0's last read (MFMA(0) at i2=6, before that bar).
    MC_WRITE(0, VA0, VA1)
    bar();
    MC_MFMA(0, S0, S1, S2, S3)
#pragma unroll
    for (int r = 0; r < 4; ++r) {
      mods2[h][ml][wl * 16 + kq * 4 + r]      = acc0[r];
      mods2[h][16 + ml][wl * 16 + kq * 4 + r] = acc1[r];
    }
#undef MC_ISSUE_A
#undef MC_ISSUE_B
#undef MC_WRITE
#undef MC_MFMA
  }
  __syncthreads();
  if (t < 576) {
    int kk = t >> 6, pxx_i = t & 63;
    float dy = mods2[0][2 * kk][pxx_i] + mods2[1][2 * kk][pxx_i]
             + mods2[2][2 * kk][pxx_i] + mods2[3][2 * kk][pxx_i];
    float dx = mods2[0][2 * kk + 1][pxx_i] + mods2[1][2 * kk + 1][pxx_i]
             + mods2[2][2 * kk + 1][pxx_i] + mods2[3][2 * kk + 1][pxx_i];
    float mv = mods2[0][18 + kk][pxx_i] + mods2[1][18 + kk][pxx_i]
             + mods2[2][18 + kk][pxx_i] + mods2[3][18 + kk][pxx_i];
    float msk = 1.f / (1.f + __expf(-mv));
    int ky = kk / 3, kx = kk - 3 * ky;
    float py  = dy + (float)(y + ky - 1);
    float pxx = dx + (float)(pxx_i + kx - 1);
    float y0f = floorf(py), x0f = floorf(pxx);
    float fy = py - y0f, fx = pxx - x0f;
    int y0 = (int)y0f, x0 = (int)x0f;
    float vy0 = (y0 >= 0 && y0 < 64) ? msk : 0.f;
    float vy1 = (y0 + 1 >= 0 && y0 + 1 < 64) ? msk : 0.f;
    float w00 = (1.f - fy) * (1.f - fx) * vy0;
    float w01 = (1.f - fy) * fx * vy0;
    float w10 = fy * (1.f - fx) * vy1;
    float w11 = fy * fx * vy1;
    int xb2 = min(max(x0, 0), 62);
    float wA0 = (xb2 == x0) ? w00 : ((xb2 == x0 + 1) ? w01 : 0.f);
    float wB0 = (xb2 + 1 == x0) ? w00 : ((xb2 + 1 == x0 + 1) ? w01 : 0.f);
    float wA1 = (xb2 == x0) ? w10 : ((xb2 == x0 + 1) ? w11 : 0.f);
    float wB1 = (xb2 + 1 == x0) ? w10 : ((xb2 + 1 == x0 + 1) ? w11 : 0.f);
    int ib0 = min(max(y0, 0), 63) * 64 + xb2;
    int ib1 = min(max(y0 + 1, 0), 63) * 64 + xb2;
    Ci[t] = make_int2(ib0, ib1);
    Cw[t] = make_float4(wA0, wB0, wA1, wB1);
  }
  __syncthreads();   // Ci/Cw visible; As1/mods2 dead -> As2/Bsl reuse region

  // ===== phase 2: 16 waves, dual-half staging, 4-buf 1-bar, deep prefetch ==
  {
    int cp = t >> 9;                       // staging half: chunk parity
    int gm = (t >> 3) & 63, go = t & 7;    // round-9 mapping within each half
    int nrow0 = (w << 4) + ml;             // wave w: n in [w*16, w*16+16)

    f32x4 zero = {0.f, 0.f, 0.f, 0.f};
    f32x4 acc[4];
#pragma unroll
    for (int i = 0; i < 4; ++i) acc[i] = zero;

    uint4 A00, A01, A02, A03; float4 wt0;   // A set 0 (this half's even chunk)
    uint4 A10, A11, A12, A13; float4 wt1;   // A set 1 (this half's odd chunk)
    uint4 SA0, SA2;                         // B pieces (chunk c4)
    uint4 SB0, SB2;                         // B pieces (chunk c4+1)
    uint4 TA0, TA2;                         // B pieces (chunk c4+2)
    uint4 TB0, TB2;                         // B pieces (chunk c4+3)

#define ISSUE_A(chunk, a0, a1, a2, a3, wt)                                   \
  { int kk_ = (chunk) >> 2, c0_ = ((chunk) & 3) << 6;                        \
    int cI_ = (kk_ << 6) + gm;                                               \
    int2 ib_ = Ci[cI_];                                                      \
    wt = Cw[cI_];                                                            \
    const u16* p0_ = xTb + (ib_.x << 8) + c0_ + (go << 3);                   \
    const u16* p1_ = xTb + (ib_.y << 8) + c0_ + (go << 3);                   \
    a0 = *(const uint4*)p0_;  a1 = *(const uint4*)(p0_ + 256);               \
    a2 = *(const uint4*)p1_;  a3 = *(const uint4*)(p1_ + 256); }

// W4: wave's 16-row block for chunk is 2KB contiguous at chunk*16384 + w*1024.
// Lane l loads pieces l*8 and 512 + l*8 (u16): rows w*16+(l>>3), w*16+8+(l>>3).
#define ISSUE_B(chunk, P0, P1)                                               \
  { const u16* pw_ = W2 + (chunk) * 16384 + (w << 10) + (l << 3);            \
    P0 = *(const uint4*)(pw_);                                               \
    P1 = *(const uint4*)(pw_ + 512); }

#define UNPACK(CUR, a0, a1, a2, a3, wt)                                      \
  { u32 q0_ = bil2(a0.x, a1.x, a2.x, a3.x, wt);                              \
    u32 q1_ = bil2(a0.y, a1.y, a2.y, a3.y, wt);                              \
    u32 q2_ = bil2(a0.z, a1.z, a2.z, a3.z, wt);                              \
    u32 q3_ = bil2(a0.w, a1.w, a2.w, a3.w, wt);                              \
    *(uint4*)&As2[CUR][gm][go << 3] = make_uint4(q0_, q1_, q2_, q3_); }

// Redistribute pieces via wave-private slab, then MFMA with the verified
// fragment addresses: b0 = slab[ml][kq*8], b1 = slab[ml][32+kq*8].
#define DOMFMA(CUR, P0, P1)                                                  \
  { *(uint4*)&Bsl[w][l >> 3][(l & 7) << 3] = P0;                             \
    *(uint4*)&Bsl[w][8 + (l >> 3)][(l & 7) << 3] = P1;                       \
    bf16x8 b0_ = *(const bf16x8*)&Bsl[w][ml][kq << 3];                       \
    bf16x8 a0_ = *(const bf16x8*)&As2[CUR][ml][kq << 3];                     \
    bf16x8 a1_ = *(const bf16x8*)&As2[CUR][16 + ml][kq << 3];                \
    bf16x8 a2_ = *(const bf16x8*)&As2[CUR][32 + ml][kq << 3];                \
    bf16x8 a3_ = *(const bf16x8*)&As2[CUR][48 + ml][kq << 3];                \
    acc[0] = __builtin_amdgcn_mfma_f32_16x16x32_bf16(a0_, b0_, acc[0], 0,0,0); \
    acc[1] = __builtin_amdgcn_mfma_f32_16x16x32_bf16(a1_, b0_, acc[1], 0,0,0); \
    acc[2] = __builtin_amdgcn_mfma_f32_16x16x32_bf16(a2_, b0_, acc[2], 0,0,0); \
    acc[3] = __builtin_amdgcn_mfma_f32_16x16x32_bf16(a3_, b0_, acc[3], 0,0,0); \
    bf16x8 b1_ = *(const bf16x8*)&Bsl[w][ml][32 + (kq << 3)];                \
    a0_ = *(const bf16x8*)&As2[CUR][ml][32 + (kq << 3)];                     \
    a1_ = *(const bf16x8*)&As2[CUR][16 + ml][32 + (kq << 3)];                \
    a2_ = *(const bf16x8*)&As2[CUR][32 + ml][32 + (kq << 3)];                \
    a3_ = *(const bf16x8*)&As2[CUR][48 + ml][32 + (kq << 3)];                \
    acc[0] = __builtin_amdgcn_mfma_f32_16x16x32_bf16(a0_, b1_, acc[0], 0,0,0); \
    acc[1] = __builtin_amdgcn_mfma_f32_16x16x32_bf16(a1_, b1_, acc[1], 0,0,0); \
    acc[2] = __builtin_amdgcn_mfma_f32_16x16x32_bf16(a2_, b1_, acc[2], 0,0,0); \
    acc[3] = __builtin_amdgcn_mfma_f32_16x16x32_bf16(a3_, b1_, acc[3], 0,0,0); }

    ISSUE_A(0 + cp, A00, A01, A02, A03, wt0)   // half cp stages chunk 0+cp
    ISSUE_A(2 + cp, A10, A11, A12, A13, wt1)   // and chunk 2+cp
    ISSUE_B(0, SA0, SA2)
    ISSUE_B(1, SB0, SB2)
#pragma unroll 1
    for (int p2 = 0; p2 < 9; ++p2) {
      int c4 = p2 << 2;
      // ---- even sub-iter: bufs 0,1 <- chunks c4, c4+1 (one per half) -----
      UNPACK(0 + cp, A00, A01, A02, A03, wt0)
      bar();
      if (p2 < 8) ISSUE_A(c4 + 4 + cp, A00, A01, A02, A03, wt0)
      ISSUE_B(c4 + 2, TA0, TA2)
      ISSUE_B(c4 + 3, TB0, TB2)
      DOMFMA(0, SA0, SA2)
      DOMFMA(1, SB0, SB2)
      // ---- odd sub-iter: bufs 2,3 <- chunks c4+2, c4+3 -------------------
      UNPACK(2 + cp, A10, A11, A12, A13, wt1)
      bar();
      if (p2 < 8) {
        ISSUE_A(c4 + 6 + cp, A10, A11, A12, A13, wt1)
        ISSUE_B(c4 + 4, SA0, SA2)
        ISSUE_B(c4 + 5, SB0, SB2)
      }
      DOMFMA(2, TA0, TA2)
      DOMFMA(3, TB0, TB2)
    }

    // epilogue (round-3 proven form): bias + f32 stores
    {
      int n = nrow0;
      float bias = b_def[n];
      float* op = out + (((b << 8) + n) << 12) + (y << 6);
#pragma unroll
      for (int mt = 0; mt < 4; ++mt) {
        float4 v;
        v.x = acc[mt][0] + bias;
        v.y = acc[mt][1] + bias;
        v.z = acc[mt][2] + bias;
        v.w = acc[mt][3] + bias;
        *(float4*)(op + mt * 16 + kq * 4) = v;
      }
    }
#undef ISSUE_A
#undef ISSUE_B
#undef UNPACK
#undef DOMFMA
  }
}

// -------------------- launcher --------------------
extern "C" void kernel_launch(void* const* d_in, const int* in_sizes, int n_in,
                              void* d_out, int out_size, void* d_ws, size_t ws_size,
                              hipStream_t stream) {
  const float* x     = (const float*)d_in[0];
  const float* w_mod = (const float*)d_in[1];
  const float* w_def = (const float*)d_in[2];
  const float* b_def = (const float*)d_in[3];
  float* out = (float*)d_out;
  char* ws = (char*)d_ws;
  // ws: xT 8,388,608 | W4 1,179,648 | Wm2 147,456
  u16* xT  = (u16*)(ws);
  u16* W2  = (u16*)(ws + 8388608);
  u16* Wm2 = (u16*)(ws + 8388608 + 1179648);

  hipLaunchKernelGGL(k_prep, dim3(1312), dim3(256), 0, stream, x, w_mod, w_def, xT, Wm2, W2);
  hipLaunchKernelGGL(k_fused, dim3(256), dim3(1024), 0, stream, xT, Wm2, W2, b_def, out);
}

// Round 18
// 131.171 us; speedup vs baseline: 1.1616x; 1.0477x over previous
//
#include <hip/hip_runtime.h>

typedef unsigned short u16;
typedef unsigned int u32;
typedef short bf16x8 __attribute__((ext_vector_type(8)));
typedef float f32x4 __attribute__((ext_vector_type(4)));

#define CIN 256
#define COUT 256

__device__ __forceinline__ u16 f2b(float f) {   // f32 -> bf16 RNE
  u32 u = __float_as_uint(f);
  u += 0x7fffu + ((u >> 16) & 1u);
  return (u16)(u >> 16);
}
__device__ __forceinline__ u32 packbf(float lo, float hi) {
  return (u32)f2b(lo) | ((u32)f2b(hi) << 16);
}
__device__ __forceinline__ u32 bil2(u32 u00, u32 u01, u32 u10, u32 u11, float4 wt) {
  float s0 = __uint_as_float(u00 << 16) * wt.x;
  s0 = fmaf(__uint_as_float(u01 << 16), wt.y, s0);
  s0 = fmaf(__uint_as_float(u10 << 16), wt.z, s0);
  s0 = fmaf(__uint_as_float(u11 << 16), wt.w, s0);
  float s1 = __uint_as_float(u00 & 0xffff0000u) * wt.x;
  s1 = fmaf(__uint_as_float(u01 & 0xffff0000u), wt.y, s1);
  s1 = fmaf(__uint_as_float(u10 & 0xffff0000u), wt.z, s1);
  s1 = fmaf(__uint_as_float(u11 & 0xffff0000u), wt.w, s1);
  return packbf(s0, s1);
}
// barrier that does NOT drain vmcnt: LDS-visibility only.
__device__ __forceinline__ void bar() {
  asm volatile("s_waitcnt lgkmcnt(0)\n\ts_barrier" ::: "memory");
}

// -------- K0 (fused prep): g<1024: xT transpose tile; else weight permute ----
// w_def: CHUNK-MAJOR W4[ch][n][cl] (round-16 verified).
// w_mod: NEW chunk-major Wm4[ch][n<32][cl] — same forward-map pattern.
__global__ __launch_bounds__(256) void k_prep(
    const float* __restrict__ x, const float* __restrict__ w_mod,
    const float* __restrict__ w_def,
    u16* __restrict__ xT, u16* __restrict__ Wm2, u16* __restrict__ W2) {
  __shared__ __align__(16) char SB[9216];
  int t = threadIdx.x, g = blockIdx.x;
  if (g < 1024) {            // x NCHW f32 -> xT[b][pos][c] bf16
    u16 (*T)[72] = (u16(*)[72])SB;
    int b = g >> 8, ct = (g >> 6) & 3, pt = g & 63;
    int c0 = ct << 6, pos0 = pt << 6;
    {
      int cl = t >> 2, pb = (t & 3) << 4;
      const float* p = x + (((b << 8) + c0 + cl) << 12) + pos0 + pb;
#pragma unroll
      for (int i = 0; i < 4; ++i) {
        float4 v = *(const float4*)(p + i * 4);
        int pp = pb + i * 4;
        T[pp][cl] = f2b(v.x); T[pp + 1][cl] = f2b(v.y);
        T[pp + 2][cl] = f2b(v.z); T[pp + 3][cl] = f2b(v.w);
      }
    }
    __syncthreads();
    {
      int pl = t >> 2, q = t & 3;
      u16* dst = xT + (((b << 12) + pos0 + pl) << 8) + c0 + (q << 4);
      *(uint4*)dst = *(const uint4*)&T[pl][q << 4];
      *(uint4*)(dst + 8) = *(const uint4*)&T[pl][(q << 4) + 8];
    }
  } else {                   // weight permute + f32->bf16
    float* L = (float*)SB;
    int gg = g - 1024;
    if (gg < 256) {
      const float* src = w_def + gg * 2304;
      for (int j = t; j < 2304; j += 256) L[j] = src[j];
      __syncthreads();
      for (int j = t; j < 2304; j += 256) {
        int kk = j >> 8, c = j & 255;
        int ch = (kk << 2) + (c >> 6), cl = c & 63;
        W2[ch * 16384 + gg * 64 + cl] = f2b(L[c * 9 + kk]);
      }
    } else {
      int cm = gg - 256;   // 0..31 (n rows 0..31; 27..31 zero)
      if (cm < 27) {
        const float* src = w_mod + cm * 2304;
        for (int j = t; j < 2304; j += 256) L[j] = src[j];
      }
      __syncthreads();
      for (int j = t; j < 2304; j += 256) {
        int kk = j >> 8, c = j & 255;
        int ch = (kk << 2) + (c >> 6), cl = c & 63;
        Wm2[ch * 2048 + cm * 64 + cl] = (cm < 27) ? f2b(L[c * 9 + kk]) : (u16)0;
      }
    }
  }
}

// -------- K1+K2 FUSED, 1024 threads (16 waves = 4/SIMD) ---------------------
// Phase 1: 4-way split-K + NEW coalesced Wm4 B-path (round-16 proven pattern:
// 4x16B/lane contiguous load + slab redistribute). Group slab Bslm[h]:
// all 4 waves of a group write IDENTICAL values (loads depend only on h,i,l)
// -> races benign; each wave writes everything it reads; bar() before each
// MC_MFMA separates chunk-i reads from chunk-i+1 writes.
// Phase 2: VERBATIM round-16 (W4 wave-contiguous B + wave-private slab).
// LDS: As1 73728 | mods2 33792 | Bslm 18432 -> LB 125952; phase 2 overlays
// As2 (36864) + Bsl (36864) at LB+0/+36864. +Ci/Cw = 139.8KB (<160KB).
__global__ __launch_bounds__(1024) void k_fused(
    const u16* __restrict__ xT, const u16* __restrict__ Wm2,
    const u16* __restrict__ W2, const float* __restrict__ b_def,
    float* __restrict__ out) {
  __shared__ __align__(16) char LB[125952];
  __shared__ __align__(16) int2 Ci[576];
  __shared__ __align__(16) float4 Cw[576];
  u16 (*As1)[2][64][72] = (u16 (*)[2][64][72])LB;           // phase 1: 4 grps
  float (*mods2)[32][66] = (float (*)[32][66])(LB + 73728); // phase 1 partials
  u16 (*Bslm)[32][72] = (u16 (*)[32][72])(LB + 107520);     // phase 1 B slabs
  u16 (*As2)[64][72] = (u16 (*)[64][72])LB;                 // phase 2: 4 bufs
  u16 (*Bsl)[16][72] = (u16 (*)[16][72])(LB + 36864);       // phase 2: B slabs

  int t = threadIdx.x;
  int l = t & 63;
  int w = t >> 6;          // 0..15
  int g = blockIdx.x;
  int b = (g & 7) >> 1, y = ((g >> 3) << 1) + (g & 1);
  const u16* xTb = xT + (b << 20);
  int ml = l & 15, kq = l >> 4;

  // ============ phase 1: mod conv, 4-way split-K (all 16 waves) ============
  {
    int h = t >> 8;          // K-group 0..3, chunks [9h, 9h+9)
    int wl = (t >> 6) & 3;
    int tg = t & 255;
    int px = tg >> 2, q = tg & 3;
    f32x4 zero = {0.f, 0.f, 0.f, 0.f};
    f32x4 acc0 = zero, acc1 = zero;
    uint4 VA0, VA1, VB0, VB1;
    uint4 S0, S1, S2, S3, T0, T1, T2, T3;

#define MC_ISSUE_A(i, V0, V1)                                                \
  { int ch_ = h * 9 + (i); int kk_ = ch_ >> 2, c0_ = (ch_ & 3) << 6;         \
    int ky_ = kk_ / 3, kx_ = kk_ - 3 * ky_;                                  \
    int ys_ = y + ky_ - 1, xs_ = px + kx_ - 1;                               \
    V0 = make_uint4(0, 0, 0, 0); V1 = V0;                                    \
    if (ys_ >= 0 && ys_ < 64 && xs_ >= 0 && xs_ < 64) {                      \
      const u16* p_ = xTb + (((ys_ << 6) + xs_) << 8) + c0_ + (q << 4);      \
      V0 = *(const uint4*)p_; V1 = *(const uint4*)(p_ + 8);                  \
    } }

// Wm4: chunk's 32x64 slice is 4KB contiguous at ch*2048 (u16). Lane l loads
// pieces l*8, +512, +1024, +1536: rows l>>3, 8+(l>>3), 16+(l>>3), 24+(l>>3).
#define MC_ISSUE_B(i, P0, P1, P2, P3)                                        \
  { const u16* pw_ = Wm2 + (h * 9 + (i)) * 2048 + (l << 3);                  \
    P0 = *(const uint4*)(pw_);                                               \
    P1 = *(const uint4*)(pw_ + 512);                                         \
    P2 = *(const uint4*)(pw_ + 1024);                                        \
    P3 = *(const uint4*)(pw_ + 1536); }

#define MC_WRITE(buf, V0, V1)                                                \
  { *(uint4*)&As1[h][buf][px][q << 4] = V0;                                  \
    *(uint4*)&As1[h][buf][px][(q << 4) + 8] = V1; }

// Redistribute via group slab (identical-value writes from the 4 waves),
// then MFMA with the verified fragment addresses:
// R0=slab[ml][kq*8] R1=slab[16+ml][kq*8] R2=slab[ml][32+kq*8] R3=[16+ml][32+..]
#define MC_MFMA(buf, P0, P1, P2, P3)                                         \
  { *(uint4*)&Bslm[h][l >> 3][(l & 7) << 3] = P0;                            \
    *(uint4*)&Bslm[h][8 + (l >> 3)][(l & 7) << 3] = P1;                      \
    *(uint4*)&Bslm[h][16 + (l >> 3)][(l & 7) << 3] = P2;                     \
    *(uint4*)&Bslm[h][24 + (l >> 3)][(l & 7) << 3] = P3;                     \
    bf16x8 b0_ = *(const bf16x8*)&Bslm[h][ml][kq << 3];                      \
    bf16x8 b1_ = *(const bf16x8*)&Bslm[h][16 + ml][kq << 3];                 \
    bf16x8 a0_ = *(const bf16x8*)&As1[h][buf][wl * 16 + ml][kq << 3];        \
    acc0 = __builtin_amdgcn_mfma_f32_16x16x32_bf16(a0_, b0_, acc0, 0,0,0);   \
    acc1 = __builtin_amdgcn_mfma_f32_16x16x32_bf16(a0_, b1_, acc1, 0,0,0);   \
    bf16x8 b2_ = *(const bf16x8*)&Bslm[h][ml][32 + (kq << 3)];               \
    bf16x8 b3_ = *(const bf16x8*)&Bslm[h][16 + ml][32 + (kq << 3)];          \
    bf16x8 a1_ = *(const bf16x8*)&As1[h][buf][wl * 16 + ml][32 + (kq << 3)]; \
    acc0 = __builtin_amdgcn_mfma_f32_16x16x32_bf16(a1_, b2_, acc0, 0,0,0);   \
    acc1 = __builtin_amdgcn_mfma_f32_16x16x32_bf16(a1_, b3_, acc1, 0,0,0); }

    MC_ISSUE_A(0, VA0, VA1)
    MC_ISSUE_A(1, VB0, VB1)
    MC_ISSUE_B(0, S0, S1, S2, S3)
#pragma unroll 1
    for (int i2 = 0; i2 < 8; i2 += 2) {
      MC_WRITE(0, VA0, VA1)
      bar();
      MC_ISSUE_A(i2 + 2, VA0, VA1)          // i2+2 in {2,4,6,8}, always < 9
      MC_ISSUE_B(i2 + 1, T0, T1, T2, T3)
      MC_MFMA(0, S0, S1, S2, S3)
      MC_WRITE(1, VB0, VB1)
      bar();
      if (i2 + 3 < 9) MC_ISSUE_A(i2 + 3, VB0, VB1)
      MC_ISSUE_B(i2 + 2, S0, S1, S2, S3)    // i2+2 < 9 always
      MC_MFMA(1, T0, T1, T2, T3)
    }
    // tail: chunk 9h+8 (VA holds A(8), S holds B(8)); WRITE(0) is one
    // barrier after buffer-0's last read (MFMA(0) at i2=6, before that bar).
    MC_WRITE(0, VA0, VA1)
    bar();
    MC_MFMA(0, S0, S1, S2, S3)
#pragma unroll
    for (int r = 0; r < 4; ++r) {
      mods2[h][ml][wl * 16 + kq * 4 + r]      = acc0[r];
      mods2[h][16 + ml][wl * 16 + kq * 4 + r] = acc1[r];
    }
#undef MC_ISSUE_A
#undef MC_ISSUE_B
#undef MC_WRITE
#undef MC_MFMA
  }
  __syncthreads();
  if (t < 576) {
    int kk = t >> 6, pxx_i = t & 63;
    float dy = mods2[0][2 * kk][pxx_i] + mods2[1][2 * kk][pxx_i]
             + mods2[2][2 * kk][pxx_i] + mods2[3][2 * kk][pxx_i];
    float dx = mods2[0][2 * kk + 1][pxx_i] + mods2[1][2 * kk + 1][pxx_i]
             + mods2[2][2 * kk + 1][pxx_i] + mods2[3][2 * kk + 1][pxx_i];
    float mv = mods2[0][18 + kk][pxx_i] + mods2[1][18 + kk][pxx_i]
             + mods2[2][18 + kk][pxx_i] + mods2[3][18 + kk][pxx_i];
    float msk = 1.f / (1.f + __expf(-mv));
    int ky = kk / 3, kx = kk - 3 * ky;
    float py  = dy + (float)(y + ky - 1);
    float pxx = dx + (float)(pxx_i + kx - 1);
    float y0f = floorf(py), x0f = floorf(pxx);
    float fy = py - y0f, fx = pxx - x0f;
    int y0 = (int)y0f, x0 = (int)x0f;
    float vy0 = (y0 >= 0 && y0 < 64) ? msk : 0.f;
    float vy1 = (y0 + 1 >= 0 && y0 + 1 < 64) ? msk : 0.f;
    float w00 = (1.f - fy) * (1.f - fx) * vy0;
    float w01 = (1.f - fy) * fx * vy0;
    float w10 = fy * (1.f - fx) * vy1;
    float w11 = fy * fx * vy1;
    int xb2 = min(max(x0, 0), 62);
    float wA0 = (xb2 == x0) ? w00 : ((xb2 == x0 + 1) ? w01 : 0.f);
    float wB0 = (xb2 + 1 == x0) ? w00 : ((xb2 + 1 == x0 + 1) ? w01 : 0.f);
    float wA1 = (xb2 == x0) ? w10 : ((xb2 == x0 + 1) ? w11 : 0.f);
    float wB1 = (xb2 + 1 == x0) ? w10 : ((xb2 + 1 == x0 + 1) ? w11 : 0.f);
    int ib0 = min(max(y0, 0), 63) * 64 + xb2;
    int ib1 = min(max(y0 + 1, 0), 63) * 64 + xb2;
    Ci[t] = make_int2(ib0, ib1);
    Cw[t] = make_float4(wA0, wB0, wA1, wB1);
  }
  __syncthreads();   // Ci/Cw visible; As1/mods2 dead -> As2/Bsl reuse region

  // ===== phase 2: 16 waves, dual-half staging, 4-buf 1-bar, deep prefetch ==
  // VERBATIM round-16 (passed at 137.4 us).
  {
    int cp = t >> 9;                       // staging half: chunk parity
    int gm = (t >> 3) & 63, go = t & 7;    // round-9 mapping within each half
    int nrow0 = (w << 4) + ml;             // wave w: n in [w*16, w*16+16)

    f32x4 zero = {0.f, 0.f, 0.f, 0.f};
    f32x4 acc[4];
#pragma unroll
    for (int i = 0; i < 4; ++i) acc[i] = zero;

    uint4 A00, A01, A02, A03; float4 wt0;   // A set 0 (this half's even chunk)
    uint4 A10, A11, A12, A13; float4 wt1;   // A set 1 (this half's odd chunk)
    uint4 SA0, SA2;                         // B pieces (chunk c4)
    uint4 SB0, SB2;                         // B pieces (chunk c4+1)
    uint4 TA0, TA2;                         // B pieces (chunk c4+2)
    uint4 TB0, TB2;                         // B pieces (chunk c4+3)

#define ISSUE_A(chunk, a0, a1, a2, a3, wt)                                   \
  { int kk_ = (chunk) >> 2, c0_ = ((chunk) & 3) << 6;                        \
    int cI_ = (kk_ << 6) + gm;                                               \
    int2 ib_ = Ci[cI_];                                                      \
    wt = Cw[cI_];                                                            \
    const u16* p0_ = xTb + (ib_.x << 8) + c0_ + (go << 3);                   \
    const u16* p1_ = xTb + (ib_.y << 8) + c0_ + (go << 3);                   \
    a0 = *(const uint4*)p0_;  a1 = *(const uint4*)(p0_ + 256);               \
    a2 = *(const uint4*)p1_;  a3 = *(const uint4*)(p1_ + 256); }

// W4: wave's 16-row block for chunk is 2KB contiguous at chunk*16384 + w*1024.
// Lane l loads pieces l*8 and 512 + l*8 (u16): rows w*16+(l>>3), w*16+8+(l>>3).
#define ISSUE_B(chunk, P0, P1)                                               \
  { const u16* pw_ = W2 + (chunk) * 16384 + (w << 10) + (l << 3);            \
    P0 = *(const uint4*)(pw_);                                               \
    P1 = *(const uint4*)(pw_ + 512); }

#define UNPACK(CUR, a0, a1, a2, a3, wt)                                      \
  { u32 q0_ = bil2(a0.x, a1.x, a2.x, a3.x, wt);                              \
    u32 q1_ = bil2(a0.y, a1.y, a2.y, a3.y, wt);                              \
    u32 q2_ = bil2(a0.z, a1.z, a2.z, a3.z, wt);                              \
    u32 q3_ = bil2(a0.w, a1.w, a2.w, a3.w, wt);                              \
    *(uint4*)&As2[CUR][gm][go << 3] = make_uint4(q0_, q1_, q2_, q3_); }

// Redistribute pieces via wave-private slab, then MFMA with the verified
// fragment addresses: b0 = slab[ml][kq*8], b1 = slab[ml][32+kq*8].
#define DOMFMA(CUR, P0, P1)                                                  \
  { *(uint4*)&Bsl[w][l >> 3][(l & 7) << 3] = P0;                             \
    *(uint4*)&Bsl[w][8 + (l >> 3)][(l & 7) << 3] = P1;                       \
    bf16x8 b0_ = *(const bf16x8*)&Bsl[w][ml][kq << 3];                       \
    bf16x8 a0_ = *(const bf16x8*)&As2[CUR][ml][kq << 3];                     \
    bf16x8 a1_ = *(const bf16x8*)&As2[CUR][16 + ml][kq << 3];                \
    bf16x8 a2_ = *(const bf16x8*)&As2[CUR][32 + ml][kq << 3];                \
    bf16x8 a3_ = *(const bf16x8*)&As2[CUR][48 + ml][kq << 3];                \
    acc[0] = __builtin_amdgcn_mfma_f32_16x16x32_bf16(a0_, b0_, acc[0], 0,0,0); \
    acc[1] = __builtin_amdgcn_mfma_f32_16x16x32_bf16(a1_, b0_, acc[1], 0,0,0); \
    acc[2] = __builtin_amdgcn_mfma_f32_16x16x32_bf16(a2_, b0_, acc[2], 0,0,0); \
    acc[3] = __builtin_amdgcn_mfma_f32_16x16x32_bf16(a3_, b0_, acc[3], 0,0,0); \
    bf16x8 b1_ = *(const bf16x8*)&Bsl[w][ml][32 + (kq << 3)];                \
    a0_ = *(const bf16x8*)&As2[CUR][ml][32 + (kq << 3)];                     \
    a1_ = *(const bf16x8*)&As2[CUR][16 + ml][32 + (kq << 3)];                \
    a2_ = *(const bf16x8*)&As2[CUR][32 + ml][32 + (kq << 3)];                \
    a3_ = *(const bf16x8*)&As2[CUR][48 + ml][32 + (kq << 3)];                \
    acc[0] = __builtin_amdgcn_mfma_f32_16x16x32_bf16(a0_, b1_, acc[0], 0,0,0); \
    acc[1] = __builtin_amdgcn_mfma_f32_16x16x32_bf16(a1_, b1_, acc[1], 0,0,0); \
    acc[2] = __builtin_amdgcn_mfma_f32_16x16x32_bf16(a2_, b1_, acc[2], 0,0,0); \
    acc[3] = __builtin_amdgcn_mfma_f32_16x16x32_bf16(a3_, b1_, acc[3], 0,0,0); }

    ISSUE_A(0 + cp, A00, A01, A02, A03, wt0)   // half cp stages chunk 0+cp
    ISSUE_A(2 + cp, A10, A11, A12, A13, wt1)   // and chunk 2+cp
    ISSUE_B(0, SA0, SA2)
    ISSUE_B(1, SB0, SB2)
#pragma unroll 1
    for (int p2 = 0; p2 < 9; ++p2) {
      int c4 = p2 << 2;
      // ---- even sub-iter: bufs 0,1 <- chunks c4, c4+1 (one per half) -----
      UNPACK(0 + cp, A00, A01, A02, A03, wt0)
      bar();
      if (p2 < 8) ISSUE_A(c4 + 4 + cp, A00, A01, A02, A03, wt0)
      ISSUE_B(c4 + 2, TA0, TA2)
      ISSUE_B(c4 + 3, TB0, TB2)
      DOMFMA(0, SA0, SA2)
      DOMFMA(1, SB0, SB2)
      // ---- odd sub-iter: bufs 2,3 <- chunks c4+2, c4+3 -------------------
      UNPACK(2 + cp, A10, A11, A12, A13, wt1)
      bar();
      if (p2 < 8) {
        ISSUE_A(c4 + 6 + cp, A10, A11, A12, A13, wt1)
        ISSUE_B(c4 + 4, SA0, SA2)
        ISSUE_B(c4 + 5, SB0, SB2)
      }
      DOMFMA(2, TA0, TA2)
      DOMFMA(3, TB0, TB2)
    }

    // epilogue (round-3 proven form): bias + f32 stores
    {
      int n = nrow0;
      float bias = b_def[n];
      float* op = out + (((b << 8) + n) << 12) + (y << 6);
#pragma unroll
      for (int mt = 0; mt < 4; ++mt) {
        float4 v;
        v.x = acc[mt][0] + bias;
        v.y = acc[mt][1] + bias;
        v.z = acc[mt][2] + bias;
        v.w = acc[mt][3] + bias;
        *(float4*)(op + mt * 16 + kq * 4) = v;
      }
    }
#undef ISSUE_A
#undef ISSUE_B
#undef UNPACK
#undef DOMFMA
  }
}

// -------------------- launcher --------------------
extern "C" void kernel_launch(void* const* d_in, const int* in_sizes, int n_in,
                              void* d_out, int out_size, void* d_ws, size_t ws_size,
                              hipStream_t stream) {
  const float* x     = (const float*)d_in[0];
  const float* w_mod = (const float*)d_in[1];
  const float* w_def = (const float*)d_in[2];
  const float* b_def = (const float*)d_in[3];
  float* out = (float*)d_out;
  char* ws = (char*)d_ws;
  // ws: xT 8,388,608 | W4 1,179,648 | Wm4 147,456
  u16* xT  = (u16*)(ws);
  u16* W2  = (u16*)(ws + 8388608);
  u16* Wm2 = (u16*)(ws + 8388608 + 1179648);

  hipLaunchKernelGGL(k_prep, dim3(1312), dim3(256), 0, stream, x, w_mod, w_def, xT, Wm2, W2);
  hipLaunchKernelGGL(k_fused, dim3(256), dim3(1024), 0, stream, xT, Wm2, W2, b_def, out);
}